// Round 11
// baseline (52.874 us; speedup 1.0000x reference)
//
#include <hip/hip_runtime.h>
#include <hip/hip_bf16.h>

// B=4, L=128, C=1024, D=512, fp32.
// out[b,l,c] = softmax_c( sum_d V[d]*tanh(wq[b,l,d] + uc[b,c,d]) )
// tanh(x) = 1 - 2/(e^{2x}+1); e^{2(wq+uc)} = e^{2wq}*e^{2uc}; shift-invariance
// drops sum(V):  align'[b,l,c] = sum_d (-2 V_d) * rcp(ewq[b,d,l]*euc[b,d,c]+1)
// Running-fraction over 16-d groups: n=fma(n,t,V*den); den*=t; t=fma(q,e,1);
// acc += n*rcp(den) once per 16 d  (4 VALU/elem + rcp/16).
//
// R11:
//  - gemm_mfma: depth-2 software pipeline (2 named pending reg sets,
//    unroll-2 rotation) -> ~600cyc latency budget for global loads.
//  - fused_align11: = align10 + s_setprio(1) around COMPUTE (T5; blocks are
//    phase-staggered at 4 blocks/CU).
//  - softmax5: 512 blocks x 1 row, block-reduce via shfl + LDS[8].

#define SCALE2 2.8853900817779268f  // 2*log2(e)
#define PART (4 * 128 * 1024)

typedef _Float16 f16x8 __attribute__((ext_vector_type(8)));
typedef float f32x4 __attribute__((ext_vector_type(4)));

__device__ __forceinline__ void gload16(const void* g, void* l) {
    __builtin_amdgcn_global_load_lds(
        (const __attribute__((address_space(1))) void*)g,
        (__attribute__((address_space(3))) void*)l,
        16, 0, 0);
}

// ---------------------------------------------------------------------------
// GEMM + exp2 via fp16-split MFMA, depth-2 pipelined staging.
// Block: 64 c-rows x 64 m. 4 waves; wave w owns m-slice w*16, all 64 c.
// K=512 in 16 chunks of 32. LDS: Xh/Xl/Wh/Wl [2][64][40] fp16 (40KB).
// blocks 0..63: wq (X=hidden, Mb=128); 64..575: uc (X=ctx, Mb=1024).
// ---------------------------------------------------------------------------
__global__ __launch_bounds__(256) void gemm_mfma(
    const float* __restrict__ hidden, const float* __restrict__ ctx,
    const float* __restrict__ Wmat, const float* __restrict__ Umat,
    const float* __restrict__ U_b,
    float* __restrict__ ewq_t, float* __restrict__ euc_t)
{
    __shared__ __align__(16) _Float16 Xh[2][64][40];
    __shared__ __align__(16) _Float16 Xl[2][64][40];
    __shared__ __align__(16) _Float16 Wh[2][64][40];
    __shared__ __align__(16) _Float16 Wl[2][64][40];

    const int tid  = threadIdx.x;
    const int lane = tid & 63;
    const int w    = tid >> 6;

    const float *X, *Wm, *bias;
    float* Ct;
    int m0, crow0, Mb, bshift;
    {
        int gb = blockIdx.x;
        if (gb < 64) {
            m0 = (gb & 7) * 64; crow0 = (gb >> 3) * 64;
            X = hidden; Wm = Wmat; bias = nullptr; Ct = ewq_t; Mb = 128; bshift = 7;
        } else {
            int g = gb - 64;
            m0 = (g & 7) * 64; crow0 = (g >> 3) * 64;
            X = ctx; Wm = Umat; bias = U_b; Ct = euc_t; Mb = 1024; bshift = 10;
        }
    }

    const int sr = tid >> 2;
    const int sk = (tid & 3) * 8;
    const float* xsrc = X  + (size_t)(crow0 + sr) * 512 + sk;
    const float* wsrc = Wm + (size_t)(m0    + sr) * 512 + sk;

    f32x4 acc[4];
#pragma unroll
    for (int t = 0; t < 4; ++t) acc[t] = (f32x4){0.f, 0.f, 0.f, 0.f};

    float xrA[8], wrA[8], xrB[8], wrB[8];

#define LOADRAW(xr_, wr_, chunk)                                              \
    {                                                                         \
        float4 a_ = *(const float4*)(xsrc + (chunk) * 32);                    \
        float4 b_ = *(const float4*)(xsrc + (chunk) * 32 + 4);                \
        float4 c_ = *(const float4*)(wsrc + (chunk) * 32);                    \
        float4 d_ = *(const float4*)(wsrc + (chunk) * 32 + 4);                \
        xr_[0]=a_.x; xr_[1]=a_.y; xr_[2]=a_.z; xr_[3]=a_.w;                   \
        xr_[4]=b_.x; xr_[5]=b_.y; xr_[6]=b_.z; xr_[7]=b_.w;                   \
        wr_[0]=c_.x; wr_[1]=c_.y; wr_[2]=c_.z; wr_[3]=c_.w;                   \
        wr_[4]=d_.x; wr_[5]=d_.y; wr_[6]=d_.z; wr_[7]=d_.w;                   \
    }

#define CVTWRITE(xr_, wr_, buf)                                               \
    {                                                                         \
        f16x8 xh_, xl_, wh_, wl_;                                             \
        _Pragma("unroll")                                                     \
        for (int i_ = 0; i_ < 8; ++i_) {                                      \
            xh_[i_] = (_Float16)xr_[i_];                                      \
            xl_[i_] = (_Float16)(xr_[i_] - (float)xh_[i_]);                   \
            wh_[i_] = (_Float16)wr_[i_];                                      \
            wl_[i_] = (_Float16)(wr_[i_] - (float)wh_[i_]);                   \
        }                                                                     \
        *(f16x8*)&Xh[buf][sr][sk] = xh_; *(f16x8*)&Xl[buf][sr][sk] = xl_;     \
        *(f16x8*)&Wh[buf][sr][sk] = wh_; *(f16x8*)&Wl[buf][sr][sk] = wl_;     \
    }

    const int fr = lane & 15;
    const int fk = (lane >> 4) * 8;
    const int mrow = w * 16 + fr;

#define MFMA_CHUNK(bu)                                                        \
    {                                                                         \
        const f16x8 ah = *(const f16x8*)&Wh[bu][mrow][fk];                    \
        const f16x8 al = *(const f16x8*)&Wl[bu][mrow][fk];                    \
        _Pragma("unroll")                                                     \
        for (int t = 0; t < 4; ++t) {                                         \
            const f16x8 bh = *(const f16x8*)&Xh[bu][t * 16 + fr][fk];         \
            const f16x8 bl = *(const f16x8*)&Xl[bu][t * 16 + fr][fk];         \
            acc[t] = __builtin_amdgcn_mfma_f32_16x16x32_f16(ah, bh, acc[t], 0, 0, 0); \
            acc[t] = __builtin_amdgcn_mfma_f32_16x16x32_f16(ah, bl, acc[t], 0, 0, 0); \
            acc[t] = __builtin_amdgcn_mfma_f32_16x16x32_f16(al, bh, acc[t], 0, 0, 0); \
        }                                                                     \
    }

    // prologue: chunk0 -> buf0 (via set A), chunk1 -> pending set A
    LOADRAW(xrA, wrA, 0);
    CVTWRITE(xrA, wrA, 0);
    LOADRAW(xrA, wrA, 1);
    __syncthreads();

    // iter kc: [load kc+2 -> Q] [mfma buf kc&1] [cvt+write P -> buf (kc+1)&1]
#define ITER(kc, xP, wP, xQ, wQ)                                              \
    {                                                                         \
        if ((kc) + 2 < 16) LOADRAW(xQ, wQ, (kc) + 2);                         \
        MFMA_CHUNK((kc) & 1);                                                 \
        if ((kc) + 1 < 16) CVTWRITE(xP, wP, ((kc) + 1) & 1);                  \
        __syncthreads();                                                      \
    }

#pragma unroll
    for (int kc2 = 0; kc2 < 16; kc2 += 2) {
        ITER(kc2,     xrA, wrA, xrB, wrB);
        ITER(kc2 + 1, xrB, wrB, xrA, wrA);
    }
#undef ITER
#undef MFMA_CHUNK
#undef CVTWRITE
#undef LOADRAW

    const int rbase = m0 + w * 16 + (lane >> 4) * 4;
    float bl4[4] = {0.f, 0.f, 0.f, 0.f};
    if (bias) {
        float4 t = *(const float4*)&bias[rbase];
        bl4[0] = t.x; bl4[1] = t.y; bl4[2] = t.z; bl4[3] = t.w;
    }
    const int bidx = crow0 >> bshift;
    const int cl0  = crow0 & (Mb - 1);
    float* obase = Ct + ((size_t)bidx * 512 + rbase) * Mb + cl0 + fr;
#pragma unroll
    for (int r = 0; r < 4; ++r)
#pragma unroll
        for (int t = 0; t < 4; ++t)
            obase[(size_t)r * Mb + t * 16] =
                __builtin_amdgcn_exp2f(SCALE2 * (acc[t][r] + bl4[r]));
}

// ---------------------------------------------------------------------------
// Fused align v11: running-fraction, 1 rcp / 16 d; setprio around compute.
// Block = 256c x 16l x 64d; 4 waves; wave w owns l0+w*4..+3; lane owns
// c0+4*lane..+3. 4 chunks of 16 d, gload16 double-buffered.
// Grid (4,8,32): z = b*8+h; partial h=0 -> pout, else pws[h-1].
// ---------------------------------------------------------------------------
__global__ __launch_bounds__(256) void fused_align11(
    const float* __restrict__ ewq_t,  // [4][512][128]
    const float* __restrict__ euc_t,  // [4][512][1024]
    const float* __restrict__ Vv,     // [512]
    float* __restrict__ pout, float* __restrict__ pws)
{
    __shared__ __align__(16) float uc_s[2][16][256];  // 32 KB
    __shared__ __align__(16) float wq_s[2][16][16];   // 2 KB
    __shared__ float v_s[64];

    const int tid  = threadIdx.x;
    const int lane = tid & 63;
    const int w    = __builtin_amdgcn_readfirstlane(tid >> 6);
    const int c0   = blockIdx.x * 256;   // 4
    const int l0   = blockIdx.y * 16;    // 8
    const int z    = blockIdx.z;         // 32
    const int b    = z >> 3, h = z & 7;
    const int d0   = h * 64;

    const float* ucb = euc_t + ((size_t)b * 512 + d0) * 1024 + c0;
    const float* wqb = ewq_t + ((size_t)b * 512 + d0) * 128 + l0;

    if (tid < 64) v_s[tid] = Vv[d0 + tid];

#define STAGE(buf, chunk)                                                     \
    {                                                                         \
        _Pragma("unroll")                                                     \
        for (int i_ = 0; i_ < 4; ++i_) {                                      \
            const int d_ = w * 4 + i_;                                        \
            gload16(ucb + (size_t)((chunk) * 16 + d_) * 1024 + lane * 4,      \
                    &uc_s[buf][d_][0]);                                       \
        }                                                                     \
        if (w == 0)                                                           \
            gload16(wqb + (size_t)((chunk) * 16 + (lane >> 2)) * 128 +        \
                        (lane & 3) * 4,                                       \
                    &wq_s[buf][0][0]);                                        \
    }

    float acc[4][4];
#pragma unroll
    for (int i = 0; i < 4; ++i)
#pragma unroll
        for (int k = 0; k < 4; ++k) acc[i][k] = 0.0f;

#define COMPUTE(bu, ch)                                                       \
    do {                                                                      \
        __builtin_amdgcn_s_setprio(1);                                        \
        float vr[16];                                                         \
        _Pragma("unroll")                                                     \
        for (int j_ = 0; j_ < 4; ++j_) {                                      \
            const float4 v4_ = *(const float4*)&v_s[(ch) * 16 + j_ * 4];      \
            vr[j_ * 4 + 0] = v4_.x; vr[j_ * 4 + 1] = v4_.y;                   \
            vr[j_ * 4 + 2] = v4_.z; vr[j_ * 4 + 3] = v4_.w;                   \
        }                                                                     \
        float nn[4][4], dn[4][4];                                             \
        {                                                                     \
            const float4 e = *(const float4*)&uc_s[bu][0][lane * 4];          \
            const float4 q = *(const float4*)&wq_s[bu][0][w * 4];             \
            const float ea[4] = {e.x, e.y, e.z, e.w};                         \
            const float qa[4] = {q.x, q.y, q.z, q.w};                         \
            _Pragma("unroll")                                                 \
            for (int i = 0; i < 4; ++i)                                       \
                _Pragma("unroll")                                             \
                for (int k = 0; k < 4; ++k) {                                 \
                    dn[i][k] = fmaf(qa[i], ea[k], 1.0f);                      \
                    nn[i][k] = vr[0];                                         \
                }                                                             \
        }                                                                     \
        _Pragma("unroll")                                                     \
        for (int dd = 1; dd < 16; ++dd) {                                     \
            const float4 e = *(const float4*)&uc_s[bu][dd][lane * 4];         \
            const float4 q = *(const float4*)&wq_s[bu][dd][w * 4];            \
            const float ea[4] = {e.x, e.y, e.z, e.w};                         \
            const float qa[4] = {q.x, q.y, q.z, q.w};                         \
            const float vv = vr[dd];                                          \
            _Pragma("unroll")                                                 \
            for (int i = 0; i < 4; ++i)                                       \
                _Pragma("unroll")                                             \
                for (int k = 0; k < 4; ++k) {                                 \
                    const float t_ = fmaf(qa[i], ea[k], 1.0f);                \
                    nn[i][k] = fmaf(nn[i][k], t_, vv * dn[i][k]);             \
                    dn[i][k] *= t_;                                           \
                }                                                             \
        }                                                                     \
        _Pragma("unroll")                                                     \
        for (int i = 0; i < 4; ++i)                                           \
            _Pragma("unroll")                                                 \
            for (int k = 0; k < 4; ++k)                                       \
                acc[i][k] = fmaf(nn[i][k],                                    \
                                 __builtin_amdgcn_rcpf(dn[i][k]), acc[i][k]); \
        __builtin_amdgcn_s_setprio(0);                                        \
    } while (0)

    STAGE(0, 0);
    __syncthreads();

    for (int cc = 0; cc < 2; ++cc) {
        STAGE(1, 2 * cc + 1);
        COMPUTE(0, 2 * cc);
        __syncthreads();
        if (cc == 0) STAGE(0, 2);
        COMPUTE(1, 2 * cc + 1);
        __syncthreads();
    }
#undef STAGE
#undef COMPUTE

    float* pp = (h == 0) ? pout : pws + (size_t)(h - 1) * PART;
#pragma unroll
    for (int i = 0; i < 4; ++i) {
        float4 r;
        r.x = -2.0f * acc[i][0]; r.y = -2.0f * acc[i][1];
        r.z = -2.0f * acc[i][2]; r.w = -2.0f * acc[i][3];
        *(float4*)(pp + ((size_t)b * 128 + l0 + w * 4 + i) * 1024 + c0 + lane * 4) = r;
    }
}

// softmax over rows of 1024 of (data + 7 ws partials); 1 row per block,
// 512 blocks, block-reduce via shfl + LDS.
__global__ __launch_bounds__(256) void softmax5(
    float* __restrict__ data, const float* __restrict__ pws)
{
    __shared__ float red[8];
    const int row  = blockIdx.x;
    const int tid  = threadIdx.x;
    const int w    = tid >> 6;
    const int lane = tid & 63;
    float* p = data + (size_t)row * 1024;

    float4 x = *(const float4*)(p + tid * 4);
#pragma unroll
    for (int t = 0; t < 7; ++t) {
        const float4 a =
            *(const float4*)(pws + (size_t)t * PART + (size_t)row * 1024 + tid * 4);
        x.x += a.x; x.y += a.y; x.z += a.z; x.w += a.w;
    }

    float m = fmaxf(fmaxf(x.x, x.y), fmaxf(x.z, x.w));
#pragma unroll
    for (int mask = 32; mask >= 1; mask >>= 1) m = fmaxf(m, __shfl_xor(m, mask, 64));
    if (lane == 0) red[w] = m;
    __syncthreads();
    m = fmaxf(fmaxf(red[0], red[1]), fmaxf(red[2], red[3]));

    const float LOG2E = 1.4426950408889634f;
    x.x = __builtin_amdgcn_exp2f((x.x - m) * LOG2E);
    x.y = __builtin_amdgcn_exp2f((x.y - m) * LOG2E);
    x.z = __builtin_amdgcn_exp2f((x.z - m) * LOG2E);
    x.w = __builtin_amdgcn_exp2f((x.w - m) * LOG2E);
    float s = (x.x + x.y) + (x.z + x.w);
#pragma unroll
    for (int mask = 32; mask >= 1; mask >>= 1) s += __shfl_xor(s, mask, 64);
    if (lane == 0) red[4 + w] = s;
    __syncthreads();
    s = (red[4] + red[5]) + (red[6] + red[7]);

    const float r = __builtin_amdgcn_rcpf(s);
    x.x *= r; x.y *= r; x.z *= r; x.w *= r;
    *(float4*)(p + tid * 4) = x;
}

extern "C" void kernel_launch(void* const* d_in, const int* in_sizes, int n_in,
                              void* d_out, int out_size, void* d_ws, size_t ws_size,
                              hipStream_t stream)
{
    const float* hidden = (const float*)d_in[0];  // [4,128,512]
    const float* ctx    = (const float*)d_in[1];  // [4,1024,512]
    const float* W      = (const float*)d_in[2];  // [512,512]
    const float* U      = (const float*)d_in[3];  // [512,512]
    const float* U_b    = (const float*)d_in[4];  // [512]
    const float* V      = (const float*)d_in[5];  // [512]
    float* out = (float*)d_out;                   // [4,128,1024]

    float* ewq_t = (float*)d_ws;                  // [4][512][128]   (1 MB)
    float* euc_t = ewq_t + 4 * 512 * 128;         // [4][512][1024]  (8 MB)
    float* pws   = euc_t + 4 * 512 * 1024;        // 7 x [4][128][1024] (14 MB)

    gemm_mfma<<<576, 256, 0, stream>>>(hidden, ctx, W, U, U_b, ewq_t, euc_t);
    fused_align11<<<dim3(4, 8, 32), 256, 0, stream>>>(ewq_t, euc_t, V, out, pws);
    softmax5<<<512, 256, 0, stream>>>(out, pws);
}